// Round 2
// baseline (427.499 us; speedup 1.0000x reference)
//
#include <hip/hip_runtime.h>
#include <hip/hip_bf16.h>

// tRNN fused kernel: embedding -> 6 tree-composition levels (MFMA bf16) -> cpr -> softmax
// B=8192, SIDES=2, L=64, V=10000, D=128, C=128, R=7
// R2: 512 threads / 8 waves per block (wave owns 16 d-rows), embedding write rotation.

typedef __attribute__((ext_vector_type(8))) short bf16x8;
typedef __attribute__((ext_vector_type(4))) float f32x4;

#define G 4  // trees per block (= 2 batch rows, both sides)

__device__ __forceinline__ ushort f2b(float x) {
  __hip_bfloat16 h = __float2bfloat16(x);
  union { __hip_bfloat16 h; ushort u; } cv; cv.h = h; return cv.u;
}
__device__ __forceinline__ float b2f(ushort u) {
  union { ushort u; __hip_bfloat16 h; } cv; cv.u = u; return __bfloat162float(cv.h);
}
__device__ __forceinline__ float fast_tanh(float x) {
  x = fminf(fmaxf(x, -15.f), 15.f);
  float e = __expf(2.f * x);
  return (e - 1.f) / (e + 1.f);
}

// One tree level: NODES = output nodes per tree. Inputs: rows [0, 2*NODES) of each
// tree's h (bf16, swizzled). Outputs: rows [0, NODES). Two barriers: all-read, all-write.
template<int NODES>
__device__ __forceinline__ void level_step(ushort* h, const bf16x8 (&A)[8],
                                           const float (&bias)[4],
                                           int lane, int wv) {
  constexpr int NTOT = G * NODES;            // total output nodes in block (>=4)
  constexpr int NT = (NTOT + 15) / 16;       // N-tiles of 16
  const int l15 = lane & 15, lh = lane >> 4;

  f32x4 acc[NT];
  const f32x4 zero = {0.f, 0.f, 0.f, 0.f};
#pragma unroll
  for (int nt = 0; nt < NT; ++nt) acc[nt] = zero;

#pragma unroll
  for (int nt = 0; nt < NT; ++nt) {
    int node = nt * 16 + l15;
    if constexpr (NTOT < 16) { if (node >= NTOT) node = 0; }  // clamp (reads garbage-safe)
    const int tree = node / NODES;
    const int i    = node % NODES;
    const int rbase = tree * 64;
    bf16x8 bf[8];
#pragma unroll
    for (int kt = 0; kt < 8; ++kt) {
      const int child = 2 * i + (kt >> 2);            // kt 0..3 -> left child, 4..7 -> right
      const int kk    = (kt & 3) * 32 + lh * 8;       // k within child's 128
      const int byteoff = (rbase + child) * 256 + ((kk * 2) ^ ((i & 7) << 4));
      bf[kt] = *(const bf16x8*)((const char*)h + byteoff);
    }
#pragma unroll
    for (int kt = 0; kt < 8; ++kt)
      acc[nt] = __builtin_amdgcn_mfma_f32_16x16x32_bf16(A[kt], bf[kt], acc[nt], 0, 0, 0);
  }
  __syncthreads();   // all reads of this level complete

#pragma unroll
  for (int nt = 0; nt < NT; ++nt) {
    const int node = nt * 16 + l15;
    bool valid = true;
    int node_c = node;
    if constexpr (NTOT < 16) { valid = node < NTOT; if (!valid) node_c = 0; }
    const int tree = node_c / NODES;
    const int i    = node_c % NODES;
    char* rowp = (char*)h + (tree * 64 + i) * 256;
    const int key = ((i >> 1) & 7) << 4;
    const int d0 = wv * 16 + lh * 4;
    ushort4 pk;
    pk.x = f2b(fast_tanh(acc[nt][0] + bias[0]));
    pk.y = f2b(fast_tanh(acc[nt][1] + bias[1]));
    pk.z = f2b(fast_tanh(acc[nt][2] + bias[2]));
    pk.w = f2b(fast_tanh(acc[nt][3] + bias[3]));
    if (valid) *(ushort4*)(rowp + ((d0 * 2) ^ key)) = pk;
  }
  __syncthreads();   // all writes complete before next level reads
}

__global__ __launch_bounds__(512, 2)
void trnn_kernel(const int* __restrict__ tokens, const float* __restrict__ voc_w,
                 const float* __restrict__ voc_b, const float* __restrict__ cps_w,
                 const float* __restrict__ cps_b, const float* __restrict__ cpr_w,
                 const float* __restrict__ cpr_b, const float* __restrict__ sm_w,
                 const float* __restrict__ sm_b, float* __restrict__ out) {
  __shared__ ushort h[G * 64 * 128];   // 64 KB: 4 trees x 64 rows x 128 bf16, swizzled
  __shared__ float zbuf[2 * 128];

  const int tid  = threadIdx.x;
  const int lane = tid & 63;
  const int wv   = tid >> 6;          // 0..7, wave owns d-rows [wv*16, wv*16+16)
  const int b0   = blockIdx.x * 2;

  // ---- load cps weights as A-fragments ----
  bf16x8 A[8];
  float  bias[4];
  {
    const int l15 = lane & 15, lh = lane >> 4;
    const int d = wv * 16 + l15;
#pragma unroll
    for (int kt = 0; kt < 8; ++kt) {
      const int k = kt * 32 + lh * 8;
      const float* p = cps_w + d * 256 + k;
      float4 lo = *(const float4*)p;
      float4 hi = *(const float4*)(p + 4);
      bf16x8 f;
      f[0] = f2b(lo.x); f[1] = f2b(lo.y); f[2] = f2b(lo.z); f[3] = f2b(lo.w);
      f[4] = f2b(hi.x); f[5] = f2b(hi.y); f[6] = f2b(hi.z); f[7] = f2b(hi.w);
      A[kt] = f;
    }
#pragma unroll
    for (int r = 0; r < 4; ++r)
      bias[r] = cps_b[wv * 16 + lh * 4 + r];
  }

  // ---- embedding: two threads per (tree, leaf) row, rotated writes (bank spread) ----
  {
    const int tree = tid >> 7, leaf = (tid >> 1) & 63, half = tid & 1;
    const int tok  = tokens[b0 * 128 + tree * 64 + leaf];
    const float* vw = voc_w + tok * 128 + half * 64;
    const float* vb = voc_b + half * 64;
    const int key = ((leaf >> 1) & 7) << 4;
    char* rowp = (char*)h + tree * 16384 + leaf * 256 + half * 128;
#pragma unroll
    for (int j = 0; j < 16; ++j) {
      const int c4 = (j + leaf) & 15;          // rotate start per leaf -> spread banks
      float4 v  = *(const float4*)(vw + c4 * 4);
      float4 bb = *(const float4*)(vb + c4 * 4);
      ushort4 pk;
      pk.x = f2b(v.x + bb.x); pk.y = f2b(v.y + bb.y);
      pk.z = f2b(v.z + bb.z); pk.w = f2b(v.w + bb.w);
      *(ushort4*)(rowp + (((half * 64 + c4 * 4) * 2) ^ key) - half * 128) = pk;
    }
  }
  __syncthreads();

  // ---- 6 composition levels: 64 leaves -> 1 root per tree ----
  level_step<32>(h, A, bias, lane, wv);
  level_step<16>(h, A, bias, lane, wv);
  level_step<8>(h, A, bias, lane, wv);
  level_step<4 >(h, A, bias, lane, wv);
  level_step<2 >(h, A, bias, lane, wv);
  level_step<1 >(h, A, bias, lane, wv);

  // ---- cpr: z[r][c] = leaky(root_cat[r] . cpr_w[c] + cpr_b[c]), r=0,1 batch rows ----
  if (tid < 256) {
    const int r = tid >> 7, c = tid & 127;
    const ushort* rt0 = h + (2 * r) * 8192;       // tree 2r, row 0 (key=0: linear)
    const ushort* rt1 = h + (2 * r + 1) * 8192;   // tree 2r+1, row 0
    const float* wrow = cpr_w + c * 256;
    float acc = cpr_b[c];
#pragma unroll 8
    for (int k4 = 0; k4 < 32; ++k4) {
      float4 w = *(const float4*)(wrow + k4 * 4);
      ushort4 u = *(const ushort4*)(rt0 + k4 * 4);
      acc += b2f(u.x) * w.x + b2f(u.y) * w.y + b2f(u.z) * w.z + b2f(u.w) * w.w;
    }
#pragma unroll 8
    for (int k4 = 0; k4 < 32; ++k4) {
      float4 w = *(const float4*)(wrow + 128 + k4 * 4);
      ushort4 u = *(const ushort4*)(rt1 + k4 * 4);
      acc += b2f(u.x) * w.x + b2f(u.y) * w.y + b2f(u.z) * w.z + b2f(u.w) * w.w;
    }
    zbuf[r * 128 + c] = acc > 0.f ? acc : 0.01f * acc;
  }
  __syncthreads();

  // ---- softmax head: wave 0 -> batch row 0, wave 1 -> batch row 1 ----
  if (wv < 2) {
    const int r = wv;
    float p[7];
#pragma unroll
    for (int j = 0; j < 7; ++j) {
      p[j] = zbuf[r * 128 + lane]      * sm_w[j * 128 + lane]
           + zbuf[r * 128 + 64 + lane] * sm_w[j * 128 + 64 + lane];
    }
#pragma unroll
    for (int j = 0; j < 7; ++j) {
      float v = p[j];
#pragma unroll
      for (int off = 32; off >= 1; off >>= 1) v += __shfl_xor(v, off, 64);
      p[j] = v + sm_b[j];
    }
    float mx = p[0];
#pragma unroll
    for (int j = 1; j < 7; ++j) mx = fmaxf(mx, p[j]);
    float e[7], s = 0.f;
#pragma unroll
    for (int j = 0; j < 7; ++j) { e[j] = __expf(p[j] - mx); s += e[j]; }
    const float inv = 1.f / s;
    if (lane == 0) {
#pragma unroll
      for (int j = 0; j < 7; ++j) out[(b0 + r) * 7 + j] = e[j] * inv;
    }
  }
}

extern "C" void kernel_launch(void* const* d_in, const int* in_sizes, int n_in,
                              void* d_out, int out_size, void* d_ws, size_t ws_size,
                              hipStream_t stream) {
  const int*   tokens = (const int*)  d_in[0];
  const float* voc_w  = (const float*)d_in[1];
  const float* voc_b  = (const float*)d_in[2];
  const float* cps_w  = (const float*)d_in[3];
  const float* cps_b  = (const float*)d_in[4];
  const float* cpr_w  = (const float*)d_in[5];
  const float* cpr_b  = (const float*)d_in[6];
  const float* sm_w   = (const float*)d_in[7];
  const float* sm_b   = (const float*)d_in[8];

  const int Btot = in_sizes[0] / 128;   // 8192
  dim3 grid(Btot / 2), block(512);
  trnn_kernel<<<grid, block, 0, stream>>>(tokens, voc_w, voc_b, cps_w, cps_b,
                                          cpr_w, cpr_b, sm_w, sm_b, (float*)d_out);
}

// Round 3
// 295.243 us; speedup vs baseline: 1.4480x; 1.4480x over previous
//
#include <hip/hip_runtime.h>
#include <hip/hip_bf16.h>

// tRNN fused: embedding -> 6 tree levels (MFMA bf16) -> cpr -> softmax
// R3: G=2 trees/block (1 batch row), 256 thr, k-chunk-major swizzled LDS,
//     bf16 weight pre-conversion in d_ws, 5-op tanh.
// B=8192, SIDES=2, L=64, V=10000, D=128, C=128, R=7

typedef __attribute__((ext_vector_type(8))) short bf16x8;
typedef __attribute__((ext_vector_type(4))) float f32x4;

#define VOCN (10000 * 128)
#define CPSN (128 * 256)
#define CPRN (128 * 256)

__device__ __forceinline__ uint pk2(float a, float b) {
  union { __hip_bfloat162 h2; uint u; } cv;
  cv.h2 = __float22bfloat162_rn(make_float2(a, b));
  return cv.u;
}
__device__ __forceinline__ float2 up2(uint u) {
  union { uint u; __hip_bfloat162 h2; } cv; cv.u = u;
  return __bfloat1622float2(cv.h2);
}
__device__ __forceinline__ float fast_tanh(float x) {
  float e = __builtin_amdgcn_exp2f(x * 2.88539008f);   // exp(2x)
  return 1.0f - 2.0f * __builtin_amdgcn_rcpf(e + 1.0f);
}
__device__ __forceinline__ int slotf(int r) { return r ^ ((r >> 3) & 7); }

// ---- prep: f32 -> bf16 (voc fused with bias) into d_ws ----
__global__ void prep_kernel(const float* __restrict__ voc_w, const float* __restrict__ voc_b,
                            const float* __restrict__ cps_w, const float* __restrict__ cpr_w,
                            ushort* __restrict__ ws) {
  const int i4 = (blockIdx.x * 256 + threadIdx.x) * 4;
  if (i4 >= VOCN + CPSN + CPRN) return;
  float4 v;
  if (i4 < VOCN) {
    v = *(const float4*)(voc_w + i4);
    const float4 bb = *(const float4*)(voc_b + (i4 & 127));
    v.x += bb.x; v.y += bb.y; v.z += bb.z; v.w += bb.w;
  } else if (i4 < VOCN + CPSN) {
    v = *(const float4*)(cps_w + (i4 - VOCN));
  } else {
    v = *(const float4*)(cpr_w + (i4 - VOCN - CPSN));
  }
  uint2 w; w.x = pk2(v.x, v.y); w.y = pk2(v.z, v.w);
  *(uint2*)(ws + i4) = w;
}

// LDS layout per tree (16 KB): elem k of row r at byte
//   (k>>3)*1024 + slot(r)*16 + (k&7)*2 , slot(r)=r^((r>>3)&7)  -> conflict-free level reads
template<int NODES>
__device__ __forceinline__ void level_step(char* hb, const bf16x8 (&A)[2][8],
                                           const float* __restrict__ cps_b,
                                           int l15, int lh, int wv) {
  constexpr int NTOT = 2 * NODES;
  constexpr int NT = (NTOT + 15) / 16;
  constexpr int LOG = NODES == 32 ? 5 : NODES == 16 ? 4 : NODES == 8 ? 3 :
                      NODES == 4 ? 2 : NODES == 2 ? 1 : 0;
  f32x4 acc[NT][2];
  const f32x4 zero = {0.f, 0.f, 0.f, 0.f};
#pragma unroll
  for (int nt = 0; nt < NT; ++nt) { acc[nt][0] = zero; acc[nt][1] = zero; }

#pragma unroll
  for (int nt = 0; nt < NT; ++nt) {
    int node = nt * 16 + l15;
    if constexpr (NTOT < 16) node = node < NTOT ? node : NTOT - 1;
    const int tree = node >> LOG;
    const int i = node & (NODES - 1);
    const char* tb = hb + tree * 16384 + lh * 1024;
    const int s0 = slotf(2 * i) * 16;        // left child slot
    const int s1 = slotf(2 * i + 1) * 16;    // right child slot
    bf16x8 bl[4], br[4];
#pragma unroll
    for (int q = 0; q < 4; ++q) bl[q] = *(const bf16x8*)(tb + q * 4096 + s0);
#pragma unroll
    for (int q = 0; q < 4; ++q) {
      acc[nt][0] = __builtin_amdgcn_mfma_f32_16x16x32_bf16(A[0][q], bl[q], acc[nt][0], 0, 0, 0);
      acc[nt][1] = __builtin_amdgcn_mfma_f32_16x16x32_bf16(A[1][q], bl[q], acc[nt][1], 0, 0, 0);
    }
#pragma unroll
    for (int q = 0; q < 4; ++q) br[q] = *(const bf16x8*)(tb + q * 4096 + s1);
#pragma unroll
    for (int q = 0; q < 4; ++q) {
      acc[nt][0] = __builtin_amdgcn_mfma_f32_16x16x32_bf16(A[0][4 + q], br[q], acc[nt][0], 0, 0, 0);
      acc[nt][1] = __builtin_amdgcn_mfma_f32_16x16x32_bf16(A[1][4 + q], br[q], acc[nt][1], 0, 0, 0);
    }
  }
  __syncthreads();   // all reads done before overwrite

#pragma unroll
  for (int nt = 0; nt < NT; ++nt) {
    int node = nt * 16 + l15;
    bool valid = true;
    if constexpr (NTOT < 16) { valid = node < NTOT; if (!valid) node = NTOT - 1; }
    const int tree = node >> LOG;
    const int i = node & (NODES - 1);
    char* tw = hb + tree * 16384 + slotf(i) * 16;
#pragma unroll
    for (int mt = 0; mt < 2; ++mt) {
      const int d0 = wv * 32 + mt * 16 + lh * 4;
      const float4 bb = *(const float4*)(cps_b + d0);
      uint2 w;
      w.x = pk2(fast_tanh(acc[nt][mt][0] + bb.x), fast_tanh(acc[nt][mt][1] + bb.y));
      w.y = pk2(fast_tanh(acc[nt][mt][2] + bb.z), fast_tanh(acc[nt][mt][3] + bb.w));
      if (valid) *(uint2*)(tw + (d0 >> 3) * 1024 + (d0 & 7) * 2) = w;
    }
  }
  __syncthreads();
}

template<int PRE>
__global__ __launch_bounds__(256, 4)
void trnn_kernel(const int* __restrict__ tokens,
                 const float* __restrict__ voc_w, const float* __restrict__ voc_b,
                 const float* __restrict__ cps_w, const float* __restrict__ cps_b,
                 const float* __restrict__ cpr_w, const float* __restrict__ cpr_b,
                 const float* __restrict__ sm_w, const float* __restrict__ sm_b,
                 const ushort* __restrict__ wsb, float* __restrict__ out) {
  __shared__ ushort h[16384];      // 32 KB: 2 trees x (16 chunks x 64 slots x 16B)
  __shared__ float partial[256];
  __shared__ float zbuf[128];
  const int tid = threadIdx.x;
  const int lane = tid & 63, wv = tid >> 6;
  const int l15 = lane & 15, lh = lane >> 4;
  const int b = blockIdx.x;
  char* hb = (char*)h;

  const ushort* voc_bf = wsb;
  const ushort* cps_bf = wsb + VOCN;
  const ushort* cpr_bf = wsb + VOCN + CPSN;

  // ---- cps weights -> A fragments (wave owns d-rows [wv*32, wv*32+32)) ----
  bf16x8 A[2][8];
#pragma unroll
  for (int mt = 0; mt < 2; ++mt) {
    const int d = wv * 32 + mt * 16 + l15;
#pragma unroll
    for (int kt = 0; kt < 8; ++kt) {
      const int k = kt * 32 + lh * 8;
      if constexpr (PRE) {
        A[mt][kt] = *(const bf16x8*)(cps_bf + d * 256 + k);
      } else {
        const float* p = cps_w + d * 256 + k;
        float4 lo = *(const float4*)p, hi = *(const float4*)(p + 4);
        union { bf16x8 v; uint4 u; } f;
        f.u.x = pk2(lo.x, lo.y); f.u.y = pk2(lo.z, lo.w);
        f.u.z = pk2(hi.x, hi.y); f.u.w = pk2(hi.z, hi.w);
        A[mt][kt] = f.v;
      }
    }
  }

  // ---- embedding: 2 threads per (tree, leaf) row ----
  {
    const int tree = tid >> 7, lf = (tid >> 1) & 63, half = tid & 1;
    const int tok = tokens[b * 128 + tree * 64 + lf];
    char* tp = hb + tree * 16384 + half * 8192 + slotf(lf) * 16;
    if constexpr (PRE) {
      const ushort* vr = voc_bf + tok * 128 + half * 64;
#pragma unroll
      for (int j = 0; j < 8; ++j) {
        const int c = (j + lf) & 7;                 // rotate -> spread chunks
        *(uint4*)(tp + c * 1024) = *(const uint4*)(vr + c * 8);
      }
    } else {
      const float* vw = voc_w + tok * 128 + half * 64;
      const float* vb = voc_b + half * 64;
#pragma unroll
      for (int j = 0; j < 8; ++j) {
        const int c = (j + lf) & 7;
        float4 v0 = *(const float4*)(vw + c * 8);
        float4 v1 = *(const float4*)(vw + c * 8 + 4);
        float4 q0 = *(const float4*)(vb + c * 8);
        float4 q1 = *(const float4*)(vb + c * 8 + 4);
        uint4 w;
        w.x = pk2(v0.x + q0.x, v0.y + q0.y);
        w.y = pk2(v0.z + q0.z, v0.w + q0.w);
        w.z = pk2(v1.x + q1.x, v1.y + q1.y);
        w.w = pk2(v1.z + q1.z, v1.w + q1.w);
        *(uint4*)(tp + c * 1024) = w;
      }
    }
  }
  __syncthreads();

  // ---- 6 levels: 64 leaves -> root per tree ----
  level_step<32>(hb, A, cps_b, l15, lh, wv);
  level_step<16>(hb, A, cps_b, l15, lh, wv);
  level_step<8>(hb, A, cps_b, l15, lh, wv);
  level_step<4>(hb, A, cps_b, l15, lh, wv);
  level_step<2>(hb, A, cps_b, l15, lh, wv);
  level_step<1>(hb, A, cps_b, l15, lh, wv);

  // ---- cpr: 2 threads per output c (one per tree-half of K) ----
  {
    const int half = tid >> 7, c = tid & 127;
    const char* rp = hb + half * 16384;   // root row 0, slot 0
    float acc = 0.f;
#pragma unroll 4
    for (int ch = 0; ch < 16; ++ch) {
      uint4 u = *(const uint4*)(rp + ch * 1024);   // broadcast within wave
      float2 e0 = up2(u.x), e1 = up2(u.y), e2 = up2(u.z), e3 = up2(u.w);
      if constexpr (PRE) {
        uint4 wq = *(const uint4*)(cpr_bf + c * 256 + half * 128 + ch * 8);
        float2 w0 = up2(wq.x), w1 = up2(wq.y), w2 = up2(wq.z), w3 = up2(wq.w);
        acc += e0.x * w0.x + e0.y * w0.y + e1.x * w1.x + e1.y * w1.y
             + e2.x * w2.x + e2.y * w2.y + e3.x * w3.x + e3.y * w3.y;
      } else {
        const float* wr = cpr_w + c * 256 + half * 128 + ch * 8;
        float4 w0 = *(const float4*)wr, w1 = *(const float4*)(wr + 4);
        acc += e0.x * w0.x + e0.y * w0.y + e1.x * w0.z + e1.y * w0.w
             + e2.x * w1.x + e2.y * w1.y + e3.x * w1.z + e3.y * w1.w;
      }
    }
    partial[half * 128 + c] = acc;
  }
  __syncthreads();
  if (tid < 128) {
    float z = partial[tid] + partial[128 + tid] + cpr_b[tid];
    zbuf[tid] = z > 0.f ? z : 0.01f * z;
  }
  __syncthreads();

  // ---- softmax head (wave 0) ----
  if (wv == 0) {
    float p[7];
#pragma unroll
    for (int j = 0; j < 7; ++j)
      p[j] = zbuf[lane] * sm_w[j * 128 + lane] + zbuf[64 + lane] * sm_w[j * 128 + 64 + lane];
#pragma unroll
    for (int j = 0; j < 7; ++j) {
      float v = p[j];
#pragma unroll
      for (int off = 32; off >= 1; off >>= 1) v += __shfl_xor(v, off, 64);
      p[j] = v + sm_b[j];
    }
    float mx = p[0];
#pragma unroll
    for (int j = 1; j < 7; ++j) mx = fmaxf(mx, p[j]);
    float e[7], s = 0.f;
#pragma unroll
    for (int j = 0; j < 7; ++j) { e[j] = __expf(p[j] - mx); s += e[j]; }
    const float inv = 1.f / s;
    if (lane == 0) {
#pragma unroll
      for (int j = 0; j < 7; ++j) out[b * 7 + j] = e[j] * inv;
    }
  }
}

extern "C" void kernel_launch(void* const* d_in, const int* in_sizes, int n_in,
                              void* d_out, int out_size, void* d_ws, size_t ws_size,
                              hipStream_t stream) {
  const int*   tokens = (const int*)  d_in[0];
  const float* voc_w  = (const float*)d_in[1];
  const float* voc_b  = (const float*)d_in[2];
  const float* cps_w  = (const float*)d_in[3];
  const float* cps_b  = (const float*)d_in[4];
  const float* cpr_w  = (const float*)d_in[5];
  const float* cpr_b  = (const float*)d_in[6];
  const float* sm_w   = (const float*)d_in[7];
  const float* sm_b   = (const float*)d_in[8];
  float* out = (float*)d_out;

  const int B = in_sizes[0] / 128;                     // 8192
  const size_t need = (size_t)(VOCN + CPSN + CPRN) * sizeof(ushort);

  if (ws_size >= need) {
    ushort* ws = (ushort*)d_ws;
    const int tot4 = (VOCN + CPSN + CPRN) / 4;
    prep_kernel<<<(tot4 + 255) / 256, 256, 0, stream>>>(voc_w, voc_b, cps_w, cpr_w, ws);
    trnn_kernel<1><<<B, 256, 0, stream>>>(tokens, voc_w, voc_b, cps_w, cps_b,
                                          cpr_w, cpr_b, sm_w, sm_b, ws, out);
  } else {
    trnn_kernel<0><<<B, 256, 0, stream>>>(tokens, voc_w, voc_b, cps_w, cps_b,
                                          cpr_w, cpr_b, sm_w, sm_b,
                                          (const ushort*)d_ws, out);
  }
}